// Round 1
// baseline (61.353 us; speedup 1.0000x reference)
//
#include <hip/hip_runtime.h>

#define N 256
#define NN 65536

typedef __attribute__((ext_vector_type(8))) __bf16 bf16x8;
typedef __attribute__((ext_vector_type(4))) __bf16 bf16x4v;
typedef __attribute__((ext_vector_type(4))) float f32x4;

// ---- workspace layout (float offsets) ----
#define F_PART   0u         // [256 blocks][256 b][32 ml]  yadj partials (2,097,152 f)
#define F_SPART  2097152u   // [8 mt][65536]               s_adj partials
#define F_WSC    2621440u   // [256]   colsum(W) + strided colsum(cl_bias)
#define F_WXCB   2621696u   // [65536] X @ (W+CB)^T
#define F_SFULL  2687232u   // [65536] s[b,j]
#define F_YADJ   2752768u   // [65536]
#define F_CTXB   2818304u   // 65536 bf16 (32768 floats)
#define WS_FLOATS 2851072u

static __device__ __forceinline__ f32x4 mfma16(bf16x8 a, bf16x8 b, f32x4 c) {
  return __builtin_amdgcn_mfma_f32_16x16x32_bf16(a, b, c, 0, 0, 0);
}
static __device__ __forceinline__ bf16x4v pack4(float4 v) {
  bf16x4v r;
  r[0] = (__bf16)v.x; r[1] = (__bf16)v.y; r[2] = (__bf16)v.z; r[3] = (__bf16)v.w;
  return r;
}

// ============================================================================
// kpre: blocks 0-15  : WXCB[b,m] = sum_n X[b,n]*(W[m,n]+cl_bias[m*N+n])  (MFMA)
//       block 16     : wsc[j] = sum_i (W[i,j] + cl_bias[i*N+j])
//       blocks 17-80 : new_context (second output)
//       blocks 81-112: ctx -> bf16 staging buffer for kbig
// ============================================================================
__global__ void __launch_bounds__(256) kpre(
    const float* __restrict__ X, const float* __restrict__ ctx,
    const float* __restrict__ W, const float* __restrict__ clb,
    const int* __restrict__ tptr, float* __restrict__ out,
    float* __restrict__ ws)
{
  extern __shared__ char smem[];
  const int blk = blockIdx.x;
  const int t = threadIdx.x;
  if (blk < 16) {
    const int b0 = (blk >> 2) * 64;
    const int m0 = (blk & 3) * 64;
    {
      const int row = t >> 2, q = t & 3;
      const int sw = (row & 7) << 4;
      const float4* xp = (const float4*)X + (b0 + row) * 64 + q * 16;
      const float4* wp = (const float4*)W + (m0 + row) * 64 + q * 16;
      const float4* cp = (const float4*)clb + (m0 + row) * 64 + q * 16;
      char* xs = smem;          // [64][512B] bf16, swizzled
      char* ps = smem + 32768;  // [64][512B] bf16 (W+CB), swizzled
#pragma unroll
      for (int i = 0; i < 16; ++i) {
        float4 xv = xp[i];
        *(bf16x4v*)(xs + row * 512 + ((q * 128 + i * 8) ^ sw)) = pack4(xv);
        float4 wv = wp[i];
        float4 cv = cp[i];
        float4 sv;
        sv.x = wv.x + cv.x; sv.y = wv.y + cv.y;
        sv.z = wv.z + cv.z; sv.w = wv.w + cv.w;
        *(bf16x4v*)(ps + row * 512 + ((q * 128 + i * 8) ^ sw)) = pack4(sv);
      }
    }
    __syncthreads();
    const int lane = t & 63, w = t >> 6;
    const int l15 = lane & 15, lhi = lane >> 4;
    const int wbl = (w >> 1) * 32, wml = (w & 1) * 32;
    const int swz = (l15 & 7) << 4;
    const f32x4 zero = {0.f, 0.f, 0.f, 0.f};
    f32x4 acc[2][2];
    acc[0][0] = zero; acc[0][1] = zero; acc[1][0] = zero; acc[1][1] = zero;
#pragma unroll
    for (int ks = 0; ks < 8; ++ks) {
      const int kb = ks * 64 + lhi * 16;
      bf16x8 a0 = *(const bf16x8*)(smem + (wbl + l15) * 512 + (kb ^ swz));
      bf16x8 a1 = *(const bf16x8*)(smem + (wbl + 16 + l15) * 512 + (kb ^ swz));
      bf16x8 b0 = *(const bf16x8*)(smem + 32768 + (wml + l15) * 512 + (kb ^ swz));
      bf16x8 b1 = *(const bf16x8*)(smem + 32768 + (wml + 16 + l15) * 512 + (kb ^ swz));
      acc[0][0] = mfma16(a0, b0, acc[0][0]);
      acc[0][1] = mfma16(a0, b1, acc[0][1]);
      acc[1][0] = mfma16(a1, b0, acc[1][0]);
      acc[1][1] = mfma16(a1, b1, acc[1][1]);
    }
#pragma unroll
    for (int fb = 0; fb < 2; ++fb)
#pragma unroll
      for (int fm = 0; fm < 2; ++fm)
#pragma unroll
        for (int r = 0; r < 4; ++r) {
          const int b = b0 + wbl + fb * 16 + lhi * 4 + r;
          const int m = m0 + wml + fm * 16 + l15;
          ws[F_WXCB + b * N + m] = acc[fb][fm][r];
        }
  } else if (blk == 16) {
    float sv = 0.f;
    for (int i = 0; i < N; ++i) sv += W[i * N + t] + clb[i * N + t];
    ws[F_WSC + t] = sv;
  } else if (blk < 81) {
    const float tf = (float)(*tptr);
    const float c1 = tf / (tf + 1.f);
    const float c2 = 1.f / (tf + 1.f);
    const int i4 = (blk - 17) * 256 + t;
    const float4 cv = ((const float4*)ctx)[i4];
    const float4 xv = ((const float4*)X)[i4];
    float4 o;
    o.x = cv.x * c1 + xv.x * c2;
    o.y = cv.y * c1 + xv.y * c2;
    o.z = cv.z * c1 + xv.z * c2;
    o.w = cv.w * c1 + xv.w * c2;
    ((float4*)out)[16384 + i4] = o;
  } else {
    const int g = (blk - 81) * 256 + t;   // 8192 groups of 8 elems
    const float4* p = (const float4*)ctx + g * 2;
    const float4 v0 = p[0], v1 = p[1];
    bf16x8 r;
    r[0] = (__bf16)v0.x; r[1] = (__bf16)v0.y; r[2] = (__bf16)v0.z; r[3] = (__bf16)v0.w;
    r[4] = (__bf16)v1.x; r[5] = (__bf16)v1.y; r[6] = (__bf16)v1.z; r[7] = (__bf16)v1.w;
    ((bf16x8*)(ws + F_CTXB))[g] = r;
  }
}

// ============================================================================
// kbig: grid 256 = 8 m-tiles x 32 n-chunks; 512 threads (8 waves x 32 b-rows)
//   per n in chunk: H_n[b, m-tile] = sum_k ctx_bf16[b,k] * clw3[m,n,k]  (MFMA)
//   yadj_acc += X[b,n] * H_n   (f32 VALU on frags)
//   s_adj partial = sum over tile-m of H_n  (shfl reduce, free colsum)
// cl_weight streamed exactly once (f32 -> bf16 reg-staged, T14 split).
// LDS: ctx[256][512B] @0 | clw[32][512B] @131072 | X[8][256]f32 @147456
// ============================================================================
__global__ void __launch_bounds__(512) kbig(
    const float* __restrict__ X, const float* __restrict__ clw,
    float* __restrict__ ws)
{
  extern __shared__ char smem[];
  char* clws = smem + 131072;
  float* xl = (float*)(smem + 147456);
  const int t = threadIdx.x;
  const int mt = blockIdx.x >> 5;
  const int s = blockIdx.x & 31;
  const int n0 = s * 8;
  const int m0g = mt * 32;
  const float4* clwf4 = (const float4*)clw;

  // prefetch clw tile (n = n0) into regs first so the HBM stream starts now
  float4 g0[4];
  int gm[4], gk[4];
#pragma unroll
  for (int i = 0; i < 4; ++i) {
    const int idx = i * 512 + t;
    gm[i] = idx >> 6;          // m within tile (0..31)
    gk[i] = idx & 63;          // float4 within row (0..63)
    g0[i] = clwf4[(m0g + gm[i]) * 16384 + n0 * 64 + gk[i]];
  }
  // stage ctx (bf16, swizzled [row][col*2B ^ ((row&7)<<4)])
  {
    const bf16x8* cb = (const bf16x8*)(ws + F_CTXB);
#pragma unroll
    for (int it = 0; it < 16; ++it) {
      const int gg = it * 512 + t;
      bf16x8 v = cb[gg];
      const int row = gg >> 5, c8 = gg & 31;
      *(bf16x8*)(smem + row * 512 + ((c8 * 16) ^ ((row & 7) << 4))) = v;
    }
  }
  // stage X slab: xl[nn][b] = X[b, n0+nn]
  if (t < 256) {
    const float4* xp = (const float4*)(X + t * N + n0);
    const float4 x0 = xp[0], x1 = xp[1];
    xl[0 * N + t] = x0.x; xl[1 * N + t] = x0.y; xl[2 * N + t] = x0.z; xl[3 * N + t] = x0.w;
    xl[4 * N + t] = x1.x; xl[5 * N + t] = x1.y; xl[6 * N + t] = x1.z; xl[7 * N + t] = x1.w;
  }
  // write clw tile n0
#pragma unroll
  for (int i = 0; i < 4; ++i) {
    *(bf16x4v*)(clws + gm[i] * 512 + ((gk[i] * 8) ^ ((gm[i] & 7) << 4))) = pack4(g0[i]);
  }
  __syncthreads();

  const int lane = t & 63, w = t >> 6;
  const int wb = w * 32, l15 = lane & 15, lhi = lane >> 4;
  const int swz = (l15 & 7) << 4;
  const f32x4 zero = {0.f, 0.f, 0.f, 0.f};
  f32x4 acc[2][2];
  acc[0][0] = zero; acc[0][1] = zero; acc[1][0] = zero; acc[1][1] = zero;

  for (int nn = 0; nn < 8; ++nn) {
    // T14: issue next n's global loads before compute
    float4 gnx[4];
    if (nn < 7) {
#pragma unroll
      for (int i = 0; i < 4; ++i)
        gnx[i] = clwf4[(m0g + gm[i]) * 16384 + (n0 + nn + 1) * 64 + gk[i]];
    }
    f32x4 h[2][2];
    h[0][0] = zero; h[0][1] = zero; h[1][0] = zero; h[1][1] = zero;
#pragma unroll
    for (int half = 0; half < 2; ++half) {
      bf16x8 af[2][4], bw[2][4];
#pragma unroll
      for (int q = 0; q < 4; ++q) {
        const int kb = half * 256 + q * 64 + lhi * 16;
        af[0][q] = *(const bf16x8*)(smem + (wb + l15) * 512 + (kb ^ swz));
        af[1][q] = *(const bf16x8*)(smem + (wb + 16 + l15) * 512 + (kb ^ swz));
        bw[0][q] = *(const bf16x8*)(clws + (l15) * 512 + (kb ^ swz));
        bw[1][q] = *(const bf16x8*)(clws + (16 + l15) * 512 + (kb ^ swz));
      }
#pragma unroll
      for (int q = 0; q < 4; ++q) {
        h[0][0] = mfma16(af[0][q], bw[0][q], h[0][0]);
        h[0][1] = mfma16(af[0][q], bw[1][q], h[0][1]);
        h[1][0] = mfma16(af[1][q], bw[0][q], h[1][0]);
        h[1][1] = mfma16(af[1][q], bw[1][q], h[1][1]);
      }
    }
    const int ng = n0 + nn;
#pragma unroll
    for (int fb = 0; fb < 2; ++fb) {
      float xv[4];
#pragma unroll
      for (int r = 0; r < 4; ++r)
        xv[r] = xl[nn * N + wb + fb * 16 + lhi * 4 + r];
#pragma unroll
      for (int r = 0; r < 4; ++r) {
        acc[fb][0][r] += xv[r] * h[fb][0][r];
        acc[fb][1][r] += xv[r] * h[fb][1][r];
        float v = h[fb][0][r] + h[fb][1][r];   // sum over fm (2 m-frags)
        v += __shfl_xor(v, 1);
        v += __shfl_xor(v, 2);
        v += __shfl_xor(v, 4);
        v += __shfl_xor(v, 8);                 // sum over 16 m-lanes
        if (l15 == 0)
          ws[F_SPART + mt * NN + (wb + fb * 16 + lhi * 4 + r) * N + ng] = v;
      }
    }
    __syncthreads();
    if (nn < 7) {
#pragma unroll
      for (int i = 0; i < 4; ++i)
        *(bf16x4v*)(clws + gm[i] * 512 + ((gk[i] * 8) ^ ((gm[i] & 7) << 4))) = pack4(gnx[i]);
    }
    __syncthreads();
  }
  // yadj partial: [block][b][ml]
  const int base = blockIdx.x * 8192;
#pragma unroll
  for (int fb = 0; fb < 2; ++fb)
#pragma unroll
    for (int fm = 0; fm < 2; ++fm)
#pragma unroll
      for (int r = 0; r < 4; ++r) {
        const int b = wb + fb * 16 + lhi * 4 + r;
        const int ml = fm * 16 + l15;
        ws[F_PART + base + b * 32 + ml] = acc[fb][fm][r];
      }
}

// ============================================================================
// kred: yadj[b,m] = sum_s part;  s_full[b,j] = wsc[j] + sum_mt spart
// ============================================================================
__global__ void __launch_bounds__(256) kred(float* __restrict__ ws)
{
  const int o = blockIdx.x * 256 + threadIdx.x;
  const int b = o >> 8, col = o & 255;
  const int mt = col >> 5, ml = col & 31;
  float y = 0.f;
#pragma unroll
  for (int si = 0; si < 32; ++si)
    y += ws[F_PART + ((mt * 32 + si) * 256 + b) * 32 + ml];
  ws[F_YADJ + o] = y;
  float sv = ws[F_WSC + col];
#pragma unroll
  for (int q = 0; q < 8; ++q)
    sv += ws[F_SPART + q * NN + o];
  ws[F_SFULL + o] = sv;
}

// ============================================================================
// kfin: d = s_full @ A (bf16 MFMA, A transposed into LDS), then
//       update[b,k] = scale*(X[b,k]*d[b,k] - WXCB[b,k] - yadj[b,k])
// ============================================================================
__global__ void __launch_bounds__(256) kfin(
    const float* __restrict__ X, const float* __restrict__ A,
    const float* __restrict__ scale, float* __restrict__ out,
    float* __restrict__ ws)
{
  extern __shared__ char smem[];  // s_tile [64][512B] @0 ; At [64][512B] @32768
  const int t = threadIdx.x, blk = blockIdx.x;
  const int b0 = (blk >> 2) * 64, k0 = (blk & 3) * 64;
  {
    const int row = t >> 2, q = t & 3;
    const int sw = (row & 7) << 4;
    const float4* sp = (const float4*)(ws + F_SFULL + (b0 + row) * N) + q * 16;
#pragma unroll
    for (int i = 0; i < 16; ++i) {
      float4 v = sp[i];
      *(bf16x4v*)(smem + row * 512 + ((q * 128 + i * 8) ^ sw)) = pack4(v);
    }
  }
  {
    const int j = t;   // 0..255
    const float4* ap = (const float4*)(A + j * N + k0);
    char* at = smem + 32768;
#pragma unroll
    for (int i = 0; i < 16; ++i) {
      float4 v = ap[i];
      const int kk = i * 4;
      *(__bf16*)(at + (kk + 0) * 512 + ((j * 2) ^ (((kk + 0) & 7) << 4))) = (__bf16)v.x;
      *(__bf16*)(at + (kk + 1) * 512 + ((j * 2) ^ (((kk + 1) & 7) << 4))) = (__bf16)v.y;
      *(__bf16*)(at + (kk + 2) * 512 + ((j * 2) ^ (((kk + 2) & 7) << 4))) = (__bf16)v.z;
      *(__bf16*)(at + (kk + 3) * 512 + ((j * 2) ^ (((kk + 3) & 7) << 4))) = (__bf16)v.w;
    }
  }
  __syncthreads();
  const int lane = t & 63, w = t >> 6;
  const int l15 = lane & 15, lhi = lane >> 4;
  const int wbl = (w >> 1) * 32, wkl = (w & 1) * 32;
  const int swz = (l15 & 7) << 4;
  const f32x4 zero = {0.f, 0.f, 0.f, 0.f};
  f32x4 acc[2][2];
  acc[0][0] = zero; acc[0][1] = zero; acc[1][0] = zero; acc[1][1] = zero;
#pragma unroll
  for (int ks = 0; ks < 8; ++ks) {
    const int kb = ks * 64 + lhi * 16;
    bf16x8 a0 = *(const bf16x8*)(smem + (wbl + l15) * 512 + (kb ^ swz));
    bf16x8 a1 = *(const bf16x8*)(smem + (wbl + 16 + l15) * 512 + (kb ^ swz));
    bf16x8 b0 = *(const bf16x8*)(smem + 32768 + (wkl + l15) * 512 + (kb ^ swz));
    bf16x8 b1 = *(const bf16x8*)(smem + 32768 + (wkl + 16 + l15) * 512 + (kb ^ swz));
    acc[0][0] = mfma16(a0, b0, acc[0][0]);
    acc[0][1] = mfma16(a0, b1, acc[0][1]);
    acc[1][0] = mfma16(a1, b0, acc[1][0]);
    acc[1][1] = mfma16(a1, b1, acc[1][1]);
  }
  const float sc = scale[0];
#pragma unroll
  for (int fb = 0; fb < 2; ++fb)
#pragma unroll
    for (int fm = 0; fm < 2; ++fm)
#pragma unroll
      for (int r = 0; r < 4; ++r) {
        const int b = b0 + wbl + fb * 16 + lhi * 4 + r;
        const int k = k0 + wkl + fm * 16 + l15;
        const int idx = b * N + k;
        const float d = acc[fb][fm][r];
        out[idx] = sc * (X[idx] * d - ws[F_WXCB + idx] - ws[F_YADJ + idx]);
      }
}

extern "C" void kernel_launch(void* const* d_in, const int* in_sizes, int n_in,
                              void* d_out, int out_size, void* d_ws, size_t ws_size,
                              hipStream_t stream)
{
  const float* X     = (const float*)d_in[0];
  const float* ctx   = (const float*)d_in[1];
  const float* W     = (const float*)d_in[2];
  const float* scale = (const float*)d_in[3];
  const float* A     = (const float*)d_in[4];
  const float* clw   = (const float*)d_in[5];
  const float* clb   = (const float*)d_in[6];
  const int*   tptr  = (const int*)d_in[7];
  float* out = (float*)d_out;
  float* ws  = (float*)d_ws;

  if (ws_size < (size_t)WS_FLOATS * sizeof(float)) return;  // need ~11 MB scratch

  (void)hipFuncSetAttribute((const void*)kpre,
                            hipFuncAttributeMaxDynamicSharedMemorySize, 65536);
  (void)hipFuncSetAttribute((const void*)kbig,
                            hipFuncAttributeMaxDynamicSharedMemorySize, 155648);
  (void)hipFuncSetAttribute((const void*)kfin,
                            hipFuncAttributeMaxDynamicSharedMemorySize, 65536);

  kpre<<<113, 256, 65536, stream>>>(X, ctx, W, clb, tptr, out, ws);
  kbig<<<256, 512, 155648, stream>>>(X, clw, ws);
  kred<<<256, 256, 0, stream>>>(ws);
  kfin<<<16, 256, 65536, stream>>>(X, A, scale, out, ws);
}

// Round 2
// 55.610 us; speedup vs baseline: 1.1033x; 1.1033x over previous
//
#include <hip/hip_runtime.h>

#define N 256
#define NN 65536

typedef __attribute__((ext_vector_type(8))) __bf16 bf16x8;
typedef __attribute__((ext_vector_type(4))) __bf16 bf16x4v;
typedef __attribute__((ext_vector_type(4))) float f32x4;

// ---- workspace layout (float offsets) ----
#define F_PART   0u         // [256 blocks][256 b][32 ml] yadj partials
#define F_SPART  2097152u   // [8 mt][65536] s_adj partials
#define F_WSC    2621440u   // [256] colsum(W)+strided colsum(cl_bias)
#define F_SFULL  2621696u   // [65536]
#define F_YADJ   2687232u   // [65536]
#define WS_FLOATS 2752768u

static __device__ __forceinline__ f32x4 mfma16(bf16x8 a, bf16x8 b, f32x4 c) {
  return __builtin_amdgcn_mfma_f32_16x16x32_bf16(a, b, c, 0, 0, 0);
}
static __device__ __forceinline__ bf16x4v pack4(float4 v) {
  bf16x4v r;
  r[0] = (__bf16)v.x; r[1] = (__bf16)v.y; r[2] = (__bf16)v.z; r[3] = (__bf16)v.w;
  return r;
}
static __device__ __forceinline__ bf16x8 pack8(float4 a, float4 b) {
  bf16x8 r;
  r[0] = (__bf16)a.x; r[1] = (__bf16)a.y; r[2] = (__bf16)a.z; r[3] = (__bf16)a.w;
  r[4] = (__bf16)b.x; r[5] = (__bf16)b.y; r[6] = (__bf16)b.z; r[7] = (__bf16)b.w;
  return r;
}

// ============================================================================
// kbig: grid 256 = 8 mt x 32 s; 512 thr (8 waves x 32 b-rows).
//   ctx A-frags hoisted to 64 VGPRs (loop-invariant, from global f32).
//   clw streamed once: depth-2 reg prefetch -> triple-buffered 16KB LDS tiles.
//   Per nn: H[b,m]=ctx@clw3[m,n,:]^T (MFMA), acc += X[b,n]*H (VALU),
//           s_adj partial = colsum_m H (shfl), one barrier.
//   mt==0 blocks also emit wsc[j] for j in [8s,8s+8).
// LDS: clw bufs 3*16KB @0 | xl[8][256]f32 @49152  (56KB)
// ============================================================================
__global__ void __launch_bounds__(512) kbig(
    const float* __restrict__ X, const float* __restrict__ ctx,
    const float* __restrict__ W, const float* __restrict__ clb,
    const float* __restrict__ clw, float* __restrict__ ws)
{
  extern __shared__ char smem[];
  float* xl = (float*)(smem + 49152);
  const int t = threadIdx.x;
  const int mt = blockIdx.x >> 5, s = blockIdx.x & 31;
  const int n0 = s * 8, m0g = mt * 32;
  const float4* clwf4 = (const float4*)clw;

  int gm[4], gk[4];
  float4 gA[4], gB[4];
#pragma unroll
  for (int i = 0; i < 4; ++i) {
    const int idx = i * 512 + t;
    gm[i] = idx >> 6; gk[i] = idx & 63;
    gA[i] = clwf4[(m0g + gm[i]) * 16384 + (n0 + 0) * 64 + gk[i]];
  }
#pragma unroll
  for (int i = 0; i < 4; ++i)
    gB[i] = clwf4[(m0g + gm[i]) * 16384 + (n0 + 1) * 64 + gk[i]];

  const int lane = t & 63, w = t >> 6;
  const int wb = w * 32, l15 = lane & 15, lhi = lane >> 4;
  const int swz = (l15 & 7) << 4;

  // hoisted ctx A-frags (each wave: its 32 b-rows, full k=256)
  bf16x8 af[2][8];
#pragma unroll
  for (int i = 0; i < 2; ++i)
#pragma unroll
    for (int c = 0; c < 8; ++c) {
      const float4* p =
          (const float4*)(ctx + (wb + i * 16 + l15) * N + c * 32 + lhi * 8);
      af[i][c] = pack8(p[0], p[1]);
    }

  if (t < 256) {  // X slab: xl[nn][b] = X[b, n0+nn]
    const float4* xp = (const float4*)(X + t * N + n0);
    const float4 x0 = xp[0], x1 = xp[1];
    xl[0 * N + t] = x0.x; xl[1 * N + t] = x0.y; xl[2 * N + t] = x0.z; xl[3 * N + t] = x0.w;
    xl[4 * N + t] = x1.x; xl[5 * N + t] = x1.y; xl[6 * N + t] = x1.z; xl[7 * N + t] = x1.w;
  }
  // write tile 0
#pragma unroll
  for (int i = 0; i < 4; ++i)
    *(bf16x4v*)(smem + gm[i] * 512 + ((gk[i] * 8) ^ ((gm[i] & 7) << 4))) = pack4(gA[i]);
  __syncthreads();

  const f32x4 zero = {0.f, 0.f, 0.f, 0.f};
  f32x4 acc[2][2];
  acc[0][0] = zero; acc[0][1] = zero; acc[1][0] = zero; acc[1][1] = zero;

#pragma unroll
  for (int nn = 0; nn < 8; ++nn) {
    // issue loads for tile nn+2 (depth-2 prefetch)
    if (nn < 6) {
      if ((nn & 1) == 0) {
#pragma unroll
        for (int i = 0; i < 4; ++i)
          gA[i] = clwf4[(m0g + gm[i]) * 16384 + (n0 + nn + 2) * 64 + gk[i]];
      } else {
#pragma unroll
        for (int i = 0; i < 4; ++i)
          gB[i] = clwf4[(m0g + gm[i]) * 16384 + (n0 + nn + 2) * 64 + gk[i]];
      }
    }
    char* buf = smem + (nn % 3) * 16384;
    f32x4 h[2][2];
    h[0][0] = zero; h[0][1] = zero; h[1][0] = zero; h[1][1] = zero;
#pragma unroll
    for (int c = 0; c < 8; ++c) {
      const int kb = c * 64 + lhi * 16;
      bf16x8 b0 = *(const bf16x8*)(buf + l15 * 512 + (kb ^ swz));
      bf16x8 b1 = *(const bf16x8*)(buf + (16 + l15) * 512 + (kb ^ swz));
      h[0][0] = mfma16(af[0][c], b0, h[0][0]);
      h[0][1] = mfma16(af[0][c], b1, h[0][1]);
      h[1][0] = mfma16(af[1][c], b0, h[1][0]);
      h[1][1] = mfma16(af[1][c], b1, h[1][1]);
    }
    const int ng = n0 + nn;
#pragma unroll
    for (int fb = 0; fb < 2; ++fb) {
#pragma unroll
      for (int r = 0; r < 4; ++r) {
        const float xv = xl[nn * N + wb + fb * 16 + lhi * 4 + r];
        acc[fb][0][r] += xv * h[fb][0][r];
        acc[fb][1][r] += xv * h[fb][1][r];
        float v = h[fb][0][r] + h[fb][1][r];
        v += __shfl_xor(v, 1);
        v += __shfl_xor(v, 2);
        v += __shfl_xor(v, 4);
        v += __shfl_xor(v, 8);
        if (l15 == 0)
          ws[F_SPART + mt * NN + (wb + fb * 16 + lhi * 4 + r) * N + ng] = v;
      }
    }
    // write tile nn+1 into buf (nn+1)%3
    if (nn < 7) {
      char* nbuf = smem + ((nn + 1) % 3) * 16384;
      if (((nn + 1) & 1) == 0) {
#pragma unroll
        for (int i = 0; i < 4; ++i)
          *(bf16x4v*)(nbuf + gm[i] * 512 + ((gk[i] * 8) ^ ((gm[i] & 7) << 4))) = pack4(gA[i]);
      } else {
#pragma unroll
        for (int i = 0; i < 4; ++i)
          *(bf16x4v*)(nbuf + gm[i] * 512 + ((gk[i] * 8) ^ ((gm[i] & 7) << 4))) = pack4(gB[i]);
      }
    }
    __syncthreads();
  }
  // yadj partials: [block][b][32 ml]
  const int base = blockIdx.x * 8192;
#pragma unroll
  for (int fb = 0; fb < 2; ++fb)
#pragma unroll
    for (int fm = 0; fm < 2; ++fm)
#pragma unroll
      for (int r = 0; r < 4; ++r)
        ws[F_PART + base + (wb + fb * 16 + lhi * 4 + r) * 32 + fm * 16 + l15] =
            acc[fb][fm][r];

  // wsc: full colsum of W+CB for 8 j-columns, by mt==0 blocks
  if (mt == 0) {
    float* red = xl;  // reuse (post-loop barrier already passed)
    if (t < 256) {
      const float4* wp = (const float4*)(W + t * N + s * 8);
      const float4* cp = (const float4*)(clb + t * N + s * 8);
      const float4 a0 = wp[0], a1 = wp[1], b0 = cp[0], b1 = cp[1];
      red[0 * 256 + t] = a0.x + b0.x; red[1 * 256 + t] = a0.y + b0.y;
      red[2 * 256 + t] = a0.z + b0.z; red[3 * 256 + t] = a0.w + b0.w;
      red[4 * 256 + t] = a1.x + b1.x; red[5 * 256 + t] = a1.y + b1.y;
      red[6 * 256 + t] = a1.z + b1.z; red[7 * 256 + t] = a1.w + b1.w;
    }
    __syncthreads();
    if (t < 64) {
      const int jj = t >> 3, seg = t & 7;
      float v = 0.f;
#pragma unroll
      for (int i = 0; i < 32; ++i) v += red[jj * 256 + seg * 32 + i];
      v += __shfl_xor(v, 1);
      v += __shfl_xor(v, 2);
      v += __shfl_xor(v, 4);
      if (seg == 0) ws[F_WSC + s * 8 + jj] = v;
    }
  }
}

// ============================================================================
// kred: yadj = sum_s partials; s_full = wsc + sum_mt spart
// ============================================================================
__global__ void __launch_bounds__(256) kred(float* __restrict__ ws)
{
  const int o = blockIdx.x * 256 + threadIdx.x;
  const int b = o >> 8, col = o & 255;
  const int mt = col >> 5, ml = col & 31;
  float y = 0.f;
#pragma unroll
  for (int si = 0; si < 32; ++si)
    y += ws[F_PART + ((mt * 32 + si) * 256 + b) * 32 + ml];
  ws[F_YADJ + o] = y;
  float sv = ws[F_WSC + col];
#pragma unroll
  for (int q = 0; q < 8; ++q)
    sv += ws[F_SPART + q * NN + o];
  ws[F_SFULL + o] = sv;
}

// ============================================================================
// kfin: 64 blocks (32b x 32k tiles), 256 thr (4 waves, one 16x16 quadrant each)
//   d = s_full @ A  and  wx = X @ (W+CB)^T   (two fused K=256 MFMA chains)
//   out = scale*(X*d - wx - yadj);  out2 = ctx*t/(t+1) + X/(t+1)
// LDS: S@0 | XT@16384 | AT@32768 | WCB@49152 (16KB each)
// ============================================================================
__global__ void __launch_bounds__(256) kfin(
    const float* __restrict__ X, const float* __restrict__ ctx,
    const float* __restrict__ W, const float* __restrict__ clb,
    const float* __restrict__ A, const float* __restrict__ scale,
    const int* __restrict__ tptr, float* __restrict__ out,
    float* __restrict__ ws)
{
  extern __shared__ char smem[];
  const int t = threadIdx.x, blk = blockIdx.x;
  const int b0 = (blk >> 3) * 32, k0 = (blk & 7) * 32;
  {
    const int row = t >> 3, q = t & 7;
    const int sw = (row & 7) << 4;
    const float4* sp = (const float4*)(ws + F_SFULL + (b0 + row) * N);
    const float4* xp = (const float4*)(X + (b0 + row) * N);
    const float4* wp = (const float4*)(W + (k0 + row) * N);
    const float4* cp = (const float4*)(clb + (k0 + row) * N);
#pragma unroll
    for (int i = 0; i < 8; ++i) {
      const int f4 = q * 8 + i;
      const int off = row * 512 + ((f4 * 8) ^ sw);
      *(bf16x4v*)(smem + off) = pack4(sp[f4]);
      *(bf16x4v*)(smem + 16384 + off) = pack4(xp[f4]);
      const float4 wv = wp[f4], cv = cp[f4];
      float4 s2;
      s2.x = wv.x + cv.x; s2.y = wv.y + cv.y;
      s2.z = wv.z + cv.z; s2.w = wv.w + cv.w;
      *(bf16x4v*)(smem + 49152 + off) = pack4(s2);
    }
    // AT[kk][j] = A[j][k0+kk]
    const float4* ap = (const float4*)(A + t * N + k0);
    char* at = smem + 32768;
#pragma unroll
    for (int i = 0; i < 8; ++i) {
      const float4 v = ap[i];
      const int kk = i * 4;
      *(__bf16*)(at + (kk + 0) * 512 + ((t * 2) ^ (((kk + 0) & 7) << 4))) = (__bf16)v.x;
      *(__bf16*)(at + (kk + 1) * 512 + ((t * 2) ^ (((kk + 1) & 7) << 4))) = (__bf16)v.y;
      *(__bf16*)(at + (kk + 2) * 512 + ((t * 2) ^ (((kk + 2) & 7) << 4))) = (__bf16)v.z;
      *(__bf16*)(at + (kk + 3) * 512 + ((t * 2) ^ (((kk + 3) & 7) << 4))) = (__bf16)v.w;
    }
  }
  __syncthreads();
  const int lane = t & 63, w = t >> 6;
  const int l15 = lane & 15, lhi = lane >> 4;
  const int wqb = (w >> 1) * 16, wqk = (w & 1) * 16;
  const int swz = (l15 & 7) << 4;
  f32x4 accd = {0.f, 0.f, 0.f, 0.f}, accw = {0.f, 0.f, 0.f, 0.f};
#pragma unroll
  for (int c = 0; c < 8; ++c) {
    const int kb = c * 64 + lhi * 16;
    bf16x8 as  = *(const bf16x8*)(smem + (wqb + l15) * 512 + (kb ^ swz));
    bf16x8 aat = *(const bf16x8*)(smem + 32768 + (wqk + l15) * 512 + (kb ^ swz));
    bf16x8 ax  = *(const bf16x8*)(smem + 16384 + (wqb + l15) * 512 + (kb ^ swz));
    bf16x8 awc = *(const bf16x8*)(smem + 49152 + (wqk + l15) * 512 + (kb ^ swz));
    accd = mfma16(as, aat, accd);
    accw = mfma16(ax, awc, accw);
  }
  const float sc = scale[0];
  const float tf = (float)(*tptr);
  const float c1 = tf / (tf + 1.f), c2 = 1.f / (tf + 1.f);
#pragma unroll
  for (int r = 0; r < 4; ++r) {
    const int b = b0 + wqb + lhi * 4 + r, k = k0 + wqk + l15;
    const int idx = b * N + k;
    const float xv = X[idx];
    out[idx] = sc * (xv * accd[r] - accw[r] - ws[F_YADJ + idx]);
    out[NN + idx] = ctx[idx] * c1 + xv * c2;
  }
}

extern "C" void kernel_launch(void* const* d_in, const int* in_sizes, int n_in,
                              void* d_out, int out_size, void* d_ws, size_t ws_size,
                              hipStream_t stream)
{
  (void)in_sizes; (void)n_in; (void)out_size;
  const float* X     = (const float*)d_in[0];
  const float* ctx   = (const float*)d_in[1];
  const float* W     = (const float*)d_in[2];
  const float* scale = (const float*)d_in[3];
  const float* A     = (const float*)d_in[4];
  const float* clw   = (const float*)d_in[5];
  const float* clb   = (const float*)d_in[6];
  const int*   tptr  = (const int*)d_in[7];
  float* out = (float*)d_out;
  float* ws  = (float*)d_ws;

  if (ws_size < (size_t)WS_FLOATS * sizeof(float)) return;

  (void)hipFuncSetAttribute((const void*)kbig,
                            hipFuncAttributeMaxDynamicSharedMemorySize, 57344);
  (void)hipFuncSetAttribute((const void*)kfin,
                            hipFuncAttributeMaxDynamicSharedMemorySize, 65536);

  kbig<<<256, 512, 57344, stream>>>(X, ctx, W, clb, clw, ws);
  kred<<<256, 256, 0, stream>>>(ws);
  kfin<<<64, 256, 65536, stream>>>(X, ctx, W, clb, A, scale, tptr, out, ws);
}

// Round 3
// 53.731 us; speedup vs baseline: 1.1419x; 1.0350x over previous
//
#include <hip/hip_runtime.h>

#define N 256
#define NN 65536

typedef __attribute__((ext_vector_type(8))) __bf16 bf16x8;
typedef __attribute__((ext_vector_type(4))) __bf16 bf16x4v;
typedef __attribute__((ext_vector_type(4))) float f32x4;

// ---- workspace layout (float offsets) ----
#define F_PART   0u         // [256 blocks][256 b][32 ml] yadj partials
#define F_SPART  2097152u   // [8 mt][256 b][256 n] s_adj partials
#define F_WSC    2621440u   // [256] colsum(W)+strided colsum(cl_bias)
#define F_SFULL  2621696u   // [65536]
#define F_YADJ   2687232u   // [65536]
#define WS_FLOATS 2752768u

static __device__ __forceinline__ f32x4 mfma16(bf16x8 a, bf16x8 b, f32x4 c) {
  return __builtin_amdgcn_mfma_f32_16x16x32_bf16(a, b, c, 0, 0, 0);
}
static __device__ __forceinline__ bf16x4v pack4(float4 v) {
  bf16x4v r;
  r[0] = (__bf16)v.x; r[1] = (__bf16)v.y; r[2] = (__bf16)v.z; r[3] = (__bf16)v.w;
  return r;
}
static __device__ __forceinline__ bf16x8 pack8(float4 a, float4 b) {
  bf16x8 r;
  r[0] = (__bf16)a.x; r[1] = (__bf16)a.y; r[2] = (__bf16)a.z; r[3] = (__bf16)a.w;
  r[4] = (__bf16)b.x; r[5] = (__bf16)b.y; r[6] = (__bf16)b.z; r[7] = (__bf16)b.w;
  return r;
}

// raw barrier: counted vmcnt stays in flight (no vmcnt(0) drain — T3/T4)
#define BAR()                                                  \
  asm volatile("s_waitcnt lgkmcnt(0)" ::: "memory");           \
  __builtin_amdgcn_s_barrier();                                \
  __builtin_amdgcn_sched_barrier(0);

// ============================================================================
// kbig: grid 256 = 8 mt x 32 s; 512 thr (8 waves x 32 b-rows).
//   ctx A-frags hoisted to 64 VGPRs. clw streamed once via depth-3 register
//   prefetch -> 3x16KB rotating LDS tiles. In-loop sync = lgkmcnt(0) + raw
//   s_barrier only; the ONLY in-loop vmem is the clw loads (counted vmcnt).
//   s_adj partials go to LDS sred[8][256], written coalesced in epilogue.
// LDS: clw bufs 3*16KB @0 | xl[8][256]f32 @49152 | sred[8][256]f32 @57344
// ============================================================================
__global__ void __launch_bounds__(512) kbig(
    const float* __restrict__ X, const float* __restrict__ ctx,
    const float* __restrict__ W, const float* __restrict__ clb,
    const float* __restrict__ clw, float* __restrict__ ws)
{
  extern __shared__ char smem[];
  float* xl = (float*)(smem + 49152);
  float* sred = (float*)(smem + 57344);
  const int t = threadIdx.x;
  const int mt = blockIdx.x >> 5, s = blockIdx.x & 31;
  const int n0 = s * 8, m0g = mt * 32;
  const float4* clwf4 = (const float4*)clw;

  int gm[4], gk[4];
  float4 g0[4], g1[4], g2[4];
#pragma unroll
  for (int i = 0; i < 4; ++i) {
    const int idx = i * 512 + t;
    gm[i] = idx >> 6; gk[i] = idx & 63;
    g0[i] = clwf4[(m0g + gm[i]) * 16384 + (n0 + 0) * 64 + gk[i]];
  }
#pragma unroll
  for (int i = 0; i < 4; ++i)
    g1[i] = clwf4[(m0g + gm[i]) * 16384 + (n0 + 1) * 64 + gk[i]];
#pragma unroll
  for (int i = 0; i < 4; ++i)
    g2[i] = clwf4[(m0g + gm[i]) * 16384 + (n0 + 2) * 64 + gk[i]];

  const int lane = t & 63, w = t >> 6;
  const int wb = w * 32, l15 = lane & 15, lhi = lane >> 4;
  const int swz = (l15 & 7) << 4;

  // hoisted ctx A-frags (each wave: its 32 b-rows, full k=256)
  bf16x8 af[2][8];
#pragma unroll
  for (int i = 0; i < 2; ++i)
#pragma unroll
    for (int c = 0; c < 8; ++c) {
      const float4* p =
          (const float4*)(ctx + (wb + i * 16 + l15) * N + c * 32 + lhi * 8);
      af[i][c] = pack8(p[0], p[1]);
    }

  if (t < 256) {  // X slab: xl[nn][b] = X[b, n0+nn]
    const float4* xp = (const float4*)(X + t * N + n0);
    const float4 x0 = xp[0], x1 = xp[1];
    xl[0 * N + t] = x0.x; xl[1 * N + t] = x0.y; xl[2 * N + t] = x0.z; xl[3 * N + t] = x0.w;
    xl[4 * N + t] = x1.x; xl[5 * N + t] = x1.y; xl[6 * N + t] = x1.z; xl[7 * N + t] = x1.w;
  }
  // write tile 0
#pragma unroll
  for (int i = 0; i < 4; ++i)
    *(bf16x4v*)(smem + gm[i] * 512 + ((gk[i] * 8) ^ ((gm[i] & 7) << 4))) = pack4(g0[i]);
  BAR();

  const f32x4 zero = {0.f, 0.f, 0.f, 0.f};
  f32x4 acc[2][2];
  acc[0][0] = zero; acc[0][1] = zero; acc[1][0] = zero; acc[1][1] = zero;

#define KITER(NN, DO_ISSUE, GISS, DO_WRITE, GWR)                              \
  {                                                                           \
    if (DO_ISSUE) {                                                           \
      _Pragma("unroll")                                                       \
      for (int i = 0; i < 4; ++i)                                             \
        GISS[i] = clwf4[(m0g + gm[i]) * 16384 + (n0 + (NN) + 3) * 64 + gk[i]];\
    }                                                                         \
    char* buf = smem + ((NN) % 3) * 16384;                                    \
    f32x4 h[2][2];                                                            \
    h[0][0] = zero; h[0][1] = zero; h[1][0] = zero; h[1][1] = zero;           \
    _Pragma("unroll")                                                         \
    for (int c = 0; c < 8; ++c) {                                             \
      const int kb = c * 64 + lhi * 16;                                       \
      bf16x8 b0 = *(const bf16x8*)(buf + l15 * 512 + (kb ^ swz));             \
      bf16x8 b1 = *(const bf16x8*)(buf + (16 + l15) * 512 + (kb ^ swz));      \
      h[0][0] = mfma16(af[0][c], b0, h[0][0]);                                \
      h[0][1] = mfma16(af[0][c], b1, h[0][1]);                                \
      h[1][0] = mfma16(af[1][c], b0, h[1][0]);                                \
      h[1][1] = mfma16(af[1][c], b1, h[1][1]);                                \
    }                                                                         \
    _Pragma("unroll")                                                         \
    for (int fb = 0; fb < 2; ++fb) {                                          \
      _Pragma("unroll")                                                       \
      for (int r = 0; r < 4; ++r) {                                           \
        const int brow = wb + fb * 16 + lhi * 4 + r;                          \
        const float xv = xl[(NN) * N + brow];                                 \
        acc[fb][0][r] += xv * h[fb][0][r];                                    \
        acc[fb][1][r] += xv * h[fb][1][r];                                    \
        float v = h[fb][0][r] + h[fb][1][r];                                  \
        v += __shfl_xor(v, 1); v += __shfl_xor(v, 2);                         \
        v += __shfl_xor(v, 4); v += __shfl_xor(v, 8);                         \
        if (l15 == 0) sred[(NN) * 256 + brow] = v;                            \
      }                                                                       \
    }                                                                         \
    if (DO_WRITE) {                                                           \
      char* wbuf = smem + (((NN) + 1) % 3) * 16384;                           \
      _Pragma("unroll")                                                       \
      for (int i = 0; i < 4; ++i)                                             \
        *(bf16x4v*)(wbuf + gm[i] * 512 +                                      \
                    ((gk[i] * 8) ^ ((gm[i] & 7) << 4))) = pack4(GWR[i]);      \
    }                                                                         \
    BAR();                                                                    \
  }

  // reg-buffer rotation: tile nn lives in g(nn%3); issue tile nn+3 into the
  // buffer freed by the LDS-write at end of iter nn-1.
  KITER(0, 1, g0, 1, g1)
  KITER(1, 1, g1, 1, g2)
  KITER(2, 1, g2, 1, g0)
  KITER(3, 1, g0, 1, g1)
  KITER(4, 1, g1, 1, g2)
  KITER(5, 0, g0, 1, g0)
  KITER(6, 0, g0, 1, g1)
  KITER(7, 0, g0, 0, g0)
#undef KITER

  // yadj partials: [block][b][32 ml] (coalesced)
  const int base = blockIdx.x * 8192;
#pragma unroll
  for (int fb = 0; fb < 2; ++fb)
#pragma unroll
    for (int fm = 0; fm < 2; ++fm)
#pragma unroll
      for (int r = 0; r < 4; ++r)
        ws[F_PART + base + (wb + fb * 16 + lhi * 4 + r) * 32 + fm * 16 + l15] =
            acc[fb][fm][r];

  // s_adj partials from sred: each wave writes its own 32 b-rows, float4 of 4 n
  {
    const int b = wb + (lane >> 1);
    const int nh = (lane & 1) * 4;
    float4 v;
    v.x = sred[(nh + 0) * 256 + b];
    v.y = sred[(nh + 1) * 256 + b];
    v.z = sred[(nh + 2) * 256 + b];
    v.w = sred[(nh + 3) * 256 + b];
    *(float4*)(ws + F_SPART + mt * NN + b * N + n0 + nh) = v;
  }

  // wsc: full colsum of W+CB for 8 j-columns, by mt==0 blocks
  if (mt == 0) {
    __syncthreads();
    float* red = xl;  // reuse
    if (t < 256) {
      const float4* wp = (const float4*)(W + t * N + s * 8);
      const float4* cp = (const float4*)(clb + t * N + s * 8);
      const float4 a0 = wp[0], a1 = wp[1], b0 = cp[0], b1 = cp[1];
      red[0 * 256 + t] = a0.x + b0.x; red[1 * 256 + t] = a0.y + b0.y;
      red[2 * 256 + t] = a0.z + b0.z; red[3 * 256 + t] = a0.w + b0.w;
      red[4 * 256 + t] = a1.x + b1.x; red[5 * 256 + t] = a1.y + b1.y;
      red[6 * 256 + t] = a1.z + b1.z; red[7 * 256 + t] = a1.w + b1.w;
    }
    __syncthreads();
    if (t < 64) {
      const int jj = t >> 3, seg = t & 7;
      float v = 0.f;
#pragma unroll
      for (int i = 0; i < 32; ++i) v += red[jj * 256 + seg * 32 + i];
      v += __shfl_xor(v, 1);
      v += __shfl_xor(v, 2);
      v += __shfl_xor(v, 4);
      if (seg == 0) ws[F_WSC + s * 8 + jj] = v;
    }
  }
}

// ============================================================================
// kred: yadj = sum_s partials; s_full = wsc + sum_mt spart
// ============================================================================
__global__ void __launch_bounds__(256) kred(float* __restrict__ ws)
{
  const int o = blockIdx.x * 256 + threadIdx.x;
  const int b = o >> 8, col = o & 255;
  const int mt = col >> 5, ml = col & 31;
  float y = 0.f;
#pragma unroll
  for (int si = 0; si < 32; ++si)
    y += ws[F_PART + ((mt * 32 + si) * 256 + b) * 32 + ml];
  ws[F_YADJ + o] = y;
  float sv = ws[F_WSC + col];
#pragma unroll
  for (int q = 0; q < 8; ++q)
    sv += ws[F_SPART + q * NN + o];
  ws[F_SFULL + o] = sv;
}

// ============================================================================
// kfin: 64 blocks (32b x 32k tiles), 256 thr (4 waves, one 16x16 quadrant each)
//   d = s_full @ A  and  wx = X @ (W+CB)^T   (two fused K=256 MFMA chains)
//   out = scale*(X*d - wx - yadj);  out2 = ctx*t/(t+1) + X/(t+1)
// LDS: S@0 | XT@16384 | AT@32768 | WCB@49152 (16KB each)
// ============================================================================
__global__ void __launch_bounds__(256) kfin(
    const float* __restrict__ X, const float* __restrict__ ctx,
    const float* __restrict__ W, const float* __restrict__ clb,
    const float* __restrict__ A, const float* __restrict__ scale,
    const int* __restrict__ tptr, float* __restrict__ out,
    float* __restrict__ ws)
{
  extern __shared__ char smem[];
  const int t = threadIdx.x, blk = blockIdx.x;
  const int b0 = (blk >> 3) * 32, k0 = (blk & 7) * 32;
  {
    const int row = t >> 3, q = t & 7;
    const int sw = (row & 7) << 4;
    const float4* sp = (const float4*)(ws + F_SFULL + (b0 + row) * N);
    const float4* xp = (const float4*)(X + (b0 + row) * N);
    const float4* wp = (const float4*)(W + (k0 + row) * N);
    const float4* cp = (const float4*)(clb + (k0 + row) * N);
#pragma unroll
    for (int i = 0; i < 8; ++i) {
      const int f4 = q * 8 + i;
      const int off = row * 512 + ((f4 * 8) ^ sw);
      *(bf16x4v*)(smem + off) = pack4(sp[f4]);
      *(bf16x4v*)(smem + 16384 + off) = pack4(xp[f4]);
      const float4 wv = wp[f4], cv = cp[f4];
      float4 s2;
      s2.x = wv.x + cv.x; s2.y = wv.y + cv.y;
      s2.z = wv.z + cv.z; s2.w = wv.w + cv.w;
      *(bf16x4v*)(smem + 49152 + off) = pack4(s2);
    }
    // AT[kk][j] = A[j][k0+kk]
    const float4* ap = (const float4*)(A + t * N + k0);
    char* at = smem + 32768;
#pragma unroll
    for (int i = 0; i < 8; ++i) {
      const float4 v = ap[i];
      const int kk = i * 4;
      *(__bf16*)(at + (kk + 0) * 512 + ((t * 2) ^ (((kk + 0) & 7) << 4))) = (__bf16)v.x;
      *(__bf16*)(at + (kk + 1) * 512 + ((t * 2) ^ (((kk + 1) & 7) << 4))) = (__bf16)v.y;
      *(__bf16*)(at + (kk + 2) * 512 + ((t * 2) ^ (((kk + 2) & 7) << 4))) = (__bf16)v.z;
      *(__bf16*)(at + (kk + 3) * 512 + ((t * 2) ^ (((kk + 3) & 7) << 4))) = (__bf16)v.w;
    }
  }
  __syncthreads();
  const int lane = t & 63, w = t >> 6;
  const int l15 = lane & 15, lhi = lane >> 4;
  const int wqb = (w >> 1) * 16, wqk = (w & 1) * 16;
  const int swz = (l15 & 7) << 4;
  f32x4 accd = {0.f, 0.f, 0.f, 0.f}, accw = {0.f, 0.f, 0.f, 0.f};
#pragma unroll
  for (int c = 0; c < 8; ++c) {
    const int kb = c * 64 + lhi * 16;
    bf16x8 as  = *(const bf16x8*)(smem + (wqb + l15) * 512 + (kb ^ swz));
    bf16x8 aat = *(const bf16x8*)(smem + 32768 + (wqk + l15) * 512 + (kb ^ swz));
    bf16x8 ax  = *(const bf16x8*)(smem + 16384 + (wqb + l15) * 512 + (kb ^ swz));
    bf16x8 awc = *(const bf16x8*)(smem + 49152 + (wqk + l15) * 512 + (kb ^ swz));
    accd = mfma16(as, aat, accd);
    accw = mfma16(ax, awc, accw);
  }
  const float sc = scale[0];
  const float tf = (float)(*tptr);
  const float c1 = tf / (tf + 1.f), c2 = 1.f / (tf + 1.f);
#pragma unroll
  for (int r = 0; r < 4; ++r) {
    const int b = b0 + wqb + lhi * 4 + r, k = k0 + wqk + l15;
    const int idx = b * N + k;
    const float xv = X[idx];
    out[idx] = sc * (xv * accd[r] - accw[r] - ws[F_YADJ + idx]);
    out[NN + idx] = ctx[idx] * c1 + xv * c2;
  }
}

extern "C" void kernel_launch(void* const* d_in, const int* in_sizes, int n_in,
                              void* d_out, int out_size, void* d_ws, size_t ws_size,
                              hipStream_t stream)
{
  (void)in_sizes; (void)n_in; (void)out_size;
  const float* X     = (const float*)d_in[0];
  const float* ctx   = (const float*)d_in[1];
  const float* W     = (const float*)d_in[2];
  const float* scale = (const float*)d_in[3];
  const float* A     = (const float*)d_in[4];
  const float* clw   = (const float*)d_in[5];
  const float* clb   = (const float*)d_in[6];
  const int*   tptr  = (const int*)d_in[7];
  float* out = (float*)d_out;
  float* ws  = (float*)d_ws;

  if (ws_size < (size_t)WS_FLOATS * sizeof(float)) return;

  (void)hipFuncSetAttribute((const void*)kbig,
                            hipFuncAttributeMaxDynamicSharedMemorySize, 65536);
  (void)hipFuncSetAttribute((const void*)kfin,
                            hipFuncAttributeMaxDynamicSharedMemorySize, 65536);

  kbig<<<256, 512, 65536, stream>>>(X, ctx, W, clb, clw, ws);
  kred<<<256, 256, 0, stream>>>(ws);
  kfin<<<64, 256, 65536, stream>>>(X, ctx, W, clb, A, scale, tptr, out, ws);
}